// Round 1
// baseline (1997.637 us; speedup 1.0000x reference)
//
#include <hip/hip_runtime.h>
#include <math.h>

// Problem constants
#define TOK   8192      // B*S
#define BQ    128       // B
#define DM    128       // D
#define NKEY  500000
#define PDIM  144       // P*DIN
#define KCHUNK 2048
#define NBLK_SIM 245    // ceil(500000/2048)
#define NCAND (NBLK_SIM*32)
#define KSPLIT 128

// ---------------- embed: out[t][d] = sum_i x[t][i]*w[i][d] + b[d] (+wpe[s][d])
__global__ __launch_bounds__(256) void k_embed(
    const float* __restrict__ x, const float* __restrict__ w,
    const float* __restrict__ b, const float* __restrict__ wpe,
    float* __restrict__ out)
{
    int idx = blockIdx.x * 256 + threadIdx.x;          // TOK*DM threads
    int t = idx >> 7, d = idx & 127;
    float acc = b[d];
    if (wpe) acc += wpe[(t & 63) * DM + d];
    const float* xr = x + t * 6;
#pragma unroll
    for (int i = 0; i < 6; i++) acc = fmaf(xr[i], w[i * DM + d], acc);
    out[idx] = acc;
}

// ---------------- layernorm: one wave per row of 128
__global__ __launch_bounds__(256) void k_ln(
    const float* __restrict__ in, const float* __restrict__ g,
    const float* __restrict__ b, float* __restrict__ out)
{
    int row = blockIdx.x * 4 + (threadIdx.x >> 6);
    int lane = threadIdx.x & 63;
    const float* r = in + row * DM;
    float v0 = r[lane], v1 = r[lane + 64];
    float s = v0 + v1, ss = v0 * v0 + v1 * v1;
#pragma unroll
    for (int o = 32; o; o >>= 1) { s += __shfl_down(s, o); ss += __shfl_down(ss, o); }
    s = __shfl(s, 0); ss = __shfl(ss, 0);
    float mean = s * (1.f / 128.f);
    float var = ss * (1.f / 128.f) - mean * mean;
    float rstd = rsqrtf(var + 1e-5f);
    out[row * DM + lane]      = (v0 - mean) * rstd * g[lane]      + b[lane];
    out[row * DM + lane + 64] = (v1 - mean) * rstd * g[lane + 64] + b[lane + 64];
}

// ---------------- generic GEMM: C[TOK x NC] = A[TOK x KD] @ W[KD x NC] + bias
// optional gelu (act=1), optional residual add (resid != null, NC==128)
template<int KD>
__global__ __launch_bounds__(256) void k_gemm(
    const float* __restrict__ A, const float* __restrict__ W,
    const float* __restrict__ bias, const float* __restrict__ resid,
    float* __restrict__ C, int NC, int act)
{
    __shared__ float As[16][68];
    __shared__ float Ws[16][68];
    const int m0 = blockIdx.x * 64, n0 = blockIdx.y * 64;
    const int tid = threadIdx.x, ty = tid >> 4, tx = tid & 15;
    float acc[4][4];
#pragma unroll
    for (int i = 0; i < 4; i++)
#pragma unroll
        for (int j = 0; j < 4; j++) acc[i][j] = 0.f;

    for (int k0 = 0; k0 < KD; k0 += 16) {
        {   // stage A tile (64 m x 16 k), transpose to k-major
            int m = tid >> 2, kk = (tid & 3) * 4;
            float4 av = *(const float4*)(A + (long)(m0 + m) * KD + k0 + kk);
            As[kk][m] = av.x; As[kk + 1][m] = av.y; As[kk + 2][m] = av.z; As[kk + 3][m] = av.w;
        }
        {   // stage W tile (16 k x 64 n)
            int kk = tid >> 4, n = (tid & 15) * 4;
            *(float4*)&Ws[kk][n] = *(const float4*)(W + (long)(k0 + kk) * NC + n0 + n);
        }
        __syncthreads();
#pragma unroll
        for (int kk = 0; kk < 16; kk++) {
            float av[4], wv[4];
            *(float4*)av = *(const float4*)&As[kk][ty * 4];
            *(float4*)wv = *(const float4*)&Ws[kk][tx * 4];
#pragma unroll
            for (int i = 0; i < 4; i++)
#pragma unroll
                for (int j = 0; j < 4; j++) acc[i][j] = fmaf(av[i], wv[j], acc[i][j]);
        }
        __syncthreads();
    }
#pragma unroll
    for (int i = 0; i < 4; i++) {
        int m = m0 + ty * 4 + i;
#pragma unroll
        for (int j = 0; j < 4; j++) {
            int n = n0 + tx * 4 + j;
            float v = acc[i][j] + bias[n];
            if (act) {
                float u = v;
                v = 0.5f * u * (1.f + tanhf(0.7978845608028654f * (u + 0.044715f * u * u * u)));
            }
            if (resid) v += resid[(long)m * NC + n];
            C[(long)m * NC + n] = v;
        }
    }
}

// ---------------- attention: one block per (b, h). S=64, hd=32, causal.
__global__ __launch_bounds__(256) void k_attn(
    const float* __restrict__ qkv, float* __restrict__ o)
{
    int b = blockIdx.x >> 2, h = blockIdx.x & 3;
    __shared__ float q[64][33], k[64][33], v[64][33];
    __shared__ float sc[64][65];
    int tid = threadIdx.x;
#pragma unroll
    for (int it = 0; it < 8; it++) {
        int idx = it * 256 + tid; int s = idx >> 5, d = idx & 31;
        const float* base = qkv + (long)(b * 64 + s) * 384 + h * 32 + d;
        q[s][d] = base[0]; k[s][d] = base[128]; v[s][d] = base[256];
    }
    __syncthreads();
    {   // scores
        int sq = tid >> 2, sk0 = (tid & 3) * 16;
        for (int j = 0; j < 16; j++) {
            int sk = sk0 + j;
            float acc = 0.f;
#pragma unroll
            for (int d = 0; d < 32; d++) acc = fmaf(q[sq][d], k[sk][d], acc);
            sc[sq][sk] = (sk <= sq) ? acc * 0.17677669529663687f : -3.0e38f;
        }
    }
    __syncthreads();
    if (tid < 64) {   // softmax, one thread per row
        float m = -3.0e38f;
        for (int j = 0; j < 64; j++) m = fmaxf(m, sc[tid][j]);
        float s = 0.f;
        for (int j = 0; j < 64; j++) { float e = __expf(sc[tid][j] - m); sc[tid][j] = e; s += e; }
        float inv = 1.f / s;
        for (int j = 0; j < 64; j++) sc[tid][j] *= inv;
    }
    __syncthreads();
#pragma unroll
    for (int it = 0; it < 8; it++) {
        int idx = it * 256 + tid; int s = idx >> 5, d = idx & 31;
        float acc = 0.f;
        for (int sk = 0; sk < 64; sk++) acc = fmaf(sc[s][sk], v[sk][d], acc);
        o[(long)(b * 64 + s) * 128 + h * 32 + d] = acc;
    }
}

// ---------------- head GEMM split-K: A[128 x 8192] @ W[8192 x NC] -> partials
template<int NC>
__global__ __launch_bounds__(256) void k_head(
    const float* __restrict__ A, const float* __restrict__ W,
    float* __restrict__ part)
{
    constexpr int NPT = NC / 16;
    __shared__ float As[16][132];
    __shared__ float Ws[16][NC + 4];
    const int tid = threadIdx.x, ty = tid >> 4, tx = tid & 15;
    float acc[8][NPT];
#pragma unroll
    for (int i = 0; i < 8; i++)
#pragma unroll
        for (int j = 0; j < NPT; j++) acc[i][j] = 0.f;
    const int kbase = blockIdx.x * 64;          // 128 blocks x 64 k
    for (int kc = 0; kc < 4; kc++) {
        int k0 = kbase + kc * 16;
        {
            int m = tid >> 1, kk = (tid & 1) * 8;
            const float* ap = A + (long)m * 8192 + k0 + kk;
            float4 a0 = *(const float4*)ap;
            float4 a1 = *(const float4*)(ap + 4);
            As[kk + 0][m] = a0.x; As[kk + 1][m] = a0.y; As[kk + 2][m] = a0.z; As[kk + 3][m] = a0.w;
            As[kk + 4][m] = a1.x; As[kk + 5][m] = a1.y; As[kk + 6][m] = a1.z; As[kk + 7][m] = a1.w;
        }
        for (int e = tid; e < 16 * NC; e += 256) {
            int kk = e / NC, n = e - kk * NC;
            Ws[kk][n] = W[(long)(k0 + kk) * NC + n];
        }
        __syncthreads();
#pragma unroll
        for (int kk = 0; kk < 16; kk++) {
            float av[8];
            *(float4*)av       = *(const float4*)&As[kk][ty * 8];
            *(float4*)(av + 4) = *(const float4*)&As[kk][ty * 8 + 4];
#pragma unroll
            for (int j = 0; j < NPT; j++) {
                float w = Ws[kk][tx * NPT + j];
#pragma unroll
                for (int i = 0; i < 8; i++) acc[i][j] = fmaf(av[i], w, acc[i][j]);
            }
        }
        __syncthreads();
    }
    float* pp = part + (long)blockIdx.x * (128 * NC);
#pragma unroll
    for (int i = 0; i < 8; i++)
#pragma unroll
        for (int j = 0; j < NPT; j++)
            pp[(ty * 8 + i) * NC + tx * NPT + j] = acc[i][j];
}

__global__ __launch_bounds__(256) void k_redhead(
    const float* __restrict__ part, const float* __restrict__ bias,
    float* __restrict__ out, int MN, int NC)
{
    int idx = blockIdx.x * 256 + threadIdx.x;
    if (idx >= MN) return;
    float s = bias[idx % NC];
    for (int b = 0; b < KSPLIT; b++) s += part[(long)b * MN + idx];
    out[idx] = s;
}

__global__ __launch_bounds__(256) void k_l2norm(float* __restrict__ qe)
{
    int row = blockIdx.x * 4 + (threadIdx.x >> 6);
    int lane = threadIdx.x & 63;
    float v0 = qe[row * 128 + lane], v1 = qe[row * 128 + 64 + lane];
    float ss = v0 * v0 + v1 * v1;
#pragma unroll
    for (int o = 32; o; o >>= 1) ss += __shfl_down(ss, o);
    ss = __shfl(ss, 0);
    float inv = 1.f / fmaxf(sqrtf(ss), 1e-12f);
    qe[row * 128 + lane] = v0 * inv;
    qe[row * 128 + 64 + lane] = v1 * inv;
}

// ---------------- sim + per-query local top-16 over a 2048-key chunk
__global__ __launch_bounds__(256) void k_sim(
    const float* __restrict__ qe, const float* __restrict__ keys,
    float* __restrict__ cval, int* __restrict__ cidx)
{
    __shared__ float qT[16][132];     // [d][q]
    __shared__ float kT[16][132];     // [d][k]
    __shared__ float simh[64][132];   // half of sim tile [q][k]
    const int tid = threadIdx.x;
    const int qt = tid >> 4, kt = tid & 15;
    const int myq = tid & 127;        // query owned for top-k
    const int kh = tid >> 7;          // key half (0/1) of each 128-tile
    const int row = myq & 63;
    const int passA = (myq < 64) ? 1 : 0;

    float tkv[16]; int tki[16];
#pragma unroll
    for (int j = 0; j < 16; j++) { tkv[j] = -3.0e38f; tki[j] = 0; }
    float runmin = -3.0e38f;

    const int kbase = blockIdx.x * KCHUNK;
    float qpre[8], kpre[8];

    for (int t = 0; t < 16; t++) {
        const int k0 = kbase + t * 128;
        float acc[8][8];
#pragma unroll
        for (int i = 0; i < 8; i++)
#pragma unroll
            for (int j = 0; j < 8; j++) acc[i][j] = 0.f;

        // prologue load (d-chunk 0)
#pragma unroll
        for (int it = 0; it < 8; it++) {
            int e = it * 256 + tid;
            int qq = e >> 4, dd = e & 15;
            qpre[it] = qe[qq * 128 + dd];
            int gk = k0 + qq;
            kpre[it] = (gk < NKEY) ? keys[(long)gk * 128 + dd] : 0.f;
        }

        for (int dc = 0; dc < 8; dc++) {
#pragma unroll
            for (int it = 0; it < 8; it++) {
                int e = it * 256 + tid;
                int qq = e >> 4, dd = e & 15;
                qT[dd][qq] = qpre[it];
                kT[dd][qq] = kpre[it];
            }
            __syncthreads();
            if (dc < 7) {   // prefetch next d-chunk during compute
                int d0n = (dc + 1) * 16;
#pragma unroll
                for (int it = 0; it < 8; it++) {
                    int e = it * 256 + tid;
                    int qq = e >> 4, dd = e & 15;
                    qpre[it] = qe[qq * 128 + d0n + dd];
                    int gk = k0 + qq;
                    kpre[it] = (gk < NKEY) ? keys[(long)gk * 128 + d0n + dd] : 0.f;
                }
            }
#pragma unroll
            for (int dd = 0; dd < 16; dd++) {
                float qv[8], kv[8];
                *(float4*)(qv)     = *(const float4*)&qT[dd][qt * 8];
                *(float4*)(qv + 4) = *(const float4*)&qT[dd][qt * 8 + 4];
                *(float4*)(kv)     = *(const float4*)&kT[dd][kt * 8];
                *(float4*)(kv + 4) = *(const float4*)&kT[dd][kt * 8 + 4];
#pragma unroll
                for (int i = 0; i < 8; i++)
#pragma unroll
                    for (int j = 0; j < 8; j++)
                        acc[i][j] = fmaf(qv[i], kv[j], acc[i][j]);
            }
            __syncthreads();
        }

        // write sim in two 64-row halves, scan each half for top-k
        for (int hh = 0; hh < 2; hh++) {
            if ((qt >> 3) == hh) {
                int r0 = (qt & 7) * 8;
#pragma unroll
                for (int i = 0; i < 8; i++) {
                    float4 v0 = make_float4(acc[i][0], acc[i][1], acc[i][2], acc[i][3]);
                    float4 v1 = make_float4(acc[i][4], acc[i][5], acc[i][6], acc[i][7]);
                    *(float4*)&simh[r0 + i][kt * 8]     = v0;
                    *(float4*)&simh[r0 + i][kt * 8 + 4] = v1;
                }
            }
            __syncthreads();
            if ((passA && hh == 0) || (!passA && hh == 1)) {
                const int ks = kh * 64;
                for (int kk = 0; kk < 64; kk++) {
                    int gk = k0 + ks + kk;
                    if (gk >= NKEY) break;
                    float v = simh[row][ks + kk];
                    if (v > runmin) {
                        int slot = 0; float mv = tkv[0];
#pragma unroll
                        for (int j = 1; j < 16; j++) if (tkv[j] < mv) { mv = tkv[j]; slot = j; }
#pragma unroll
                        for (int j = 0; j < 16; j++) if (j == slot) { tkv[j] = v; tki[j] = gk; }
                        runmin = tkv[0];
#pragma unroll
                        for (int j = 1; j < 16; j++) runmin = fminf(runmin, tkv[j]);
                    }
                }
            }
            __syncthreads();
        }
    }
    int ob = (blockIdx.x * 128 + myq) * 32 + kh * 16;
#pragma unroll
    for (int j = 0; j < 16; j++) { cval[ob + j] = tkv[j]; cidx[ob + j] = tki[j]; }
}

// ---------------- merge candidates, softmax, gather memory_values, fuse
__global__ __launch_bounds__(256) void k_merge(
    const float* __restrict__ cval, const int* __restrict__ cidx,
    const float* __restrict__ base, const float* __restrict__ mvals,
    const float* __restrict__ fw, float* __restrict__ out)
{
    __shared__ float sv[NCAND];
    __shared__ int   si[NCAND];
    __shared__ float wv[4]; __shared__ int wi[4];
    __shared__ float tv[16]; __shared__ int ti[16];
    const int q = blockIdx.x, tid = threadIdx.x;
    for (int i = tid; i < NCAND; i += 256) {
        sv[i] = cval[(i >> 5) * 4096 + q * 32 + (i & 31)];
        si[i] = cidx[(i >> 5) * 4096 + q * 32 + (i & 31)];
    }
    __syncthreads();
    for (int r = 0; r < 16; r++) {
        float bv = -3.0e38f; int bp = -1;
        for (int i = tid; i < NCAND; i += 256) {
            float v = sv[i];
            if (v > bv) { bv = v; bp = i; }
        }
#pragma unroll
        for (int o = 32; o; o >>= 1) {
            float ov = __shfl_down(bv, o); int op = __shfl_down(bp, o);
            if (ov > bv) { bv = ov; bp = op; }
        }
        if ((tid & 63) == 0) { wv[tid >> 6] = bv; wi[tid >> 6] = bp; }
        __syncthreads();
        if (tid == 0) {
            float b2 = wv[0]; int p2 = wi[0];
            for (int w = 1; w < 4; w++) if (wv[w] > b2) { b2 = wv[w]; p2 = wi[w]; }
            tv[r] = b2; ti[r] = si[p2]; sv[p2] = -3.0e38f;
        }
        __syncthreads();
    }
    float alpha = 1.f / (1.f + expf(-fw[0]));
    if (tid < PDIM) {
        float m = tv[0];
#pragma unroll
        for (int r = 1; r < 16; r++) m = fmaxf(m, tv[r]);
        float w[16]; float s = 0.f;
#pragma unroll
        for (int r = 0; r < 16; r++) { w[r] = expf(tv[r] - m); s += w[r]; }
        float inv = 1.f / s;
        float ret = 0.f;
#pragma unroll
        for (int r = 0; r < 16; r++) ret += w[r] * inv * mvals[(long)ti[r] * PDIM + tid];
        out[q * PDIM + tid] = alpha * base[q * PDIM + tid] + (1.f - alpha) * ret;
    }
}

// ---------------- launch
extern "C" void kernel_launch(void* const* d_in, const int* in_sizes, int n_in,
                              void* d_out, int out_size, void* d_ws, size_t ws_size,
                              hipStream_t stream)
{
    const float* x      = (const float*)d_in[0];
    const float* keys   = (const float*)d_in[1];
    const float* mvals  = (const float*)d_in[2];
    const float* wpe    = (const float*)d_in[3];
    const float* w_in   = (const float*)d_in[4];
    const float* b_in   = (const float*)d_in[5];
    const float* ln1_g  = (const float*)d_in[6];
    const float* ln1_b  = (const float*)d_in[7];
    const float* attn_w = (const float*)d_in[8];
    const float* attn_b = (const float*)d_in[9];
    const float* attn_pw= (const float*)d_in[10];
    const float* attn_pb= (const float*)d_in[11];
    const float* ln2_g  = (const float*)d_in[12];
    const float* ln2_b  = (const float*)d_in[13];
    const float* fc_w   = (const float*)d_in[14];
    const float* fc_b   = (const float*)d_in[15];
    const float* mlp_pw = (const float*)d_in[16];
    const float* mlp_pb = (const float*)d_in[17];
    const float* lnf_g  = (const float*)d_in[18];
    const float* lnf_b  = (const float*)d_in[19];
    const float* w_out  = (const float*)d_in[20];
    const float* b_out  = (const float*)d_in[21];
    const float* ret_w1 = (const float*)d_in[22];
    const float* ret_b1 = (const float*)d_in[23];
    const float* ret_w2 = (const float*)d_in[24];
    const float* ret_b2 = (const float*)d_in[25];
    const float* fw     = (const float*)d_in[26];
    float* out = (float*)d_out;

    float* ws   = (float*)d_ws;
    float* h    = ws + 0;           // TOK*128   = 1048576
    float* bufA = ws + 1048576;     // TOK*128
    float* bufB = ws + 2097152;     // TOK*512   = 4194304 (qkv / fc act)
    float* bufO = ws + 6291456;     // TOK*128
    float* part = ws + 7340032;     // KSPLIT*128*144 = 2359296
    float* base = ws + 9699328;     // 18432
    float* qe   = ws + 9717760;     // 16384
    float* cval = ws + 9734144;     // NCAND*128/... = 1003520
    int*   cidx = (int*)(ws + 10737664); // 1003520
    // total ~ 11.74M floats = ~47 MB

    k_embed<<<4096, 256, 0, stream>>>(x, w_in, b_in, wpe, h);
    for (int l = 0; l < 3; l++) {
        k_ln<<<2048, 256, 0, stream>>>(h, ln1_g + l * 128, ln1_b + l * 128, bufA);
        k_gemm<128><<<dim3(128, 6), 256, 0, stream>>>(bufA, attn_w + l * 49152,
            attn_b + l * 384, nullptr, bufB, 384, 0);
        k_attn<<<512, 256, 0, stream>>>(bufB, bufO);
        k_gemm<128><<<dim3(128, 2), 256, 0, stream>>>(bufO, attn_pw + l * 16384,
            attn_pb + l * 128, h, h, 128, 0);
        k_ln<<<2048, 256, 0, stream>>>(h, ln2_g + l * 128, ln2_b + l * 128, bufA);
        k_gemm<128><<<dim3(128, 8), 256, 0, stream>>>(bufA, fc_w + l * 65536,
            fc_b + l * 512, nullptr, bufB, 512, 1);
        k_gemm<512><<<dim3(128, 2), 256, 0, stream>>>(bufB, mlp_pw + l * 65536,
            mlp_pb + l * 128, h, h, 128, 0);
    }
    k_ln<<<2048, 256, 0, stream>>>(h, lnf_g, lnf_b, bufA);
    k_head<144><<<KSPLIT, 256, 0, stream>>>(bufA, w_out, part);
    k_redhead<<<72, 256, 0, stream>>>(part, b_out, base, 128 * 144, 144);

    k_embed<<<4096, 256, 0, stream>>>(x, ret_w1, ret_b1, nullptr, bufO);
    k_head<128><<<KSPLIT, 256, 0, stream>>>(bufO, ret_w2, part);
    k_redhead<<<64, 256, 0, stream>>>(part, ret_b2, qe, 128 * 128, 128);
    k_l2norm<<<32, 256, 0, stream>>>(qe);

    k_sim<<<NBLK_SIM, 256, 0, stream>>>(qe, keys, cval, cidx);
    k_merge<<<128, 256, 0, stream>>>(cval, cidx, base, mvals, fw, out);
}

// Round 2
// 1314.762 us; speedup vs baseline: 1.5194x; 1.5194x over previous
//
#include <hip/hip_runtime.h>
#include <math.h>

// Problem constants
#define TOK   8192      // B*S
#define DM    128       // D
#define NKEY  500000
#define PDIM  144       // P*DIN
#define KSPLIT 128

// sim kernel config
#define SB     256                 // sim grid (blocks)
#define NPASS  7813                // ceil(500000 / 64)
#define NCAND  (SB * 16)           // candidates per query

typedef __attribute__((ext_vector_type(8))) short short8;
typedef __attribute__((ext_vector_type(4))) float f32x4;

__device__ inline short f2bf(float x) {
    union { float f; unsigned u; } v; v.f = x;
    unsigned r = v.u + 0x7FFFu + ((v.u >> 16) & 1u);
    return (short)(r >> 16);
}
__device__ inline float bf2f(short h) {
    union { float f; unsigned u; } v;
    v.u = ((unsigned)(unsigned short)h) << 16;
    return v.f;
}

// ---------------- embed: out[t][d] = sum_i x[t][i]*w[i][d] + b[d] (+wpe[s][d])
__global__ __launch_bounds__(256) void k_embed(
    const float* __restrict__ x, const float* __restrict__ w,
    const float* __restrict__ b, const float* __restrict__ wpe,
    float* __restrict__ out)
{
    int idx = blockIdx.x * 256 + threadIdx.x;          // TOK*DM threads
    int t = idx >> 7, d = idx & 127;
    float acc = b[d];
    if (wpe) acc += wpe[(t & 63) * DM + d];
    const float* xr = x + t * 6;
#pragma unroll
    for (int i = 0; i < 6; i++) acc = fmaf(xr[i], w[i * DM + d], acc);
    out[idx] = acc;
}

// ---------------- layernorm: one wave per row of 128
__global__ __launch_bounds__(256) void k_ln(
    const float* __restrict__ in, const float* __restrict__ g,
    const float* __restrict__ b, float* __restrict__ out)
{
    int row = blockIdx.x * 4 + (threadIdx.x >> 6);
    int lane = threadIdx.x & 63;
    const float* r = in + row * DM;
    float v0 = r[lane], v1 = r[lane + 64];
    float s = v0 + v1, ss = v0 * v0 + v1 * v1;
#pragma unroll
    for (int o = 32; o; o >>= 1) { s += __shfl_down(s, o); ss += __shfl_down(ss, o); }
    s = __shfl(s, 0); ss = __shfl(ss, 0);
    float mean = s * (1.f / 128.f);
    float var = ss * (1.f / 128.f) - mean * mean;
    float rstd = rsqrtf(var + 1e-5f);
    out[row * DM + lane]      = (v0 - mean) * rstd * g[lane]      + b[lane];
    out[row * DM + lane + 64] = (v1 - mean) * rstd * g[lane + 64] + b[lane + 64];
}

// ---------------- generic GEMM: C[TOK x NC] = A[TOK x KD] @ W[KD x NC] + bias
template<int KD>
__global__ __launch_bounds__(256) void k_gemm(
    const float* __restrict__ A, const float* __restrict__ W,
    const float* __restrict__ bias, const float* __restrict__ resid,
    float* __restrict__ C, int NC, int act)
{
    __shared__ float As[16][68];
    __shared__ float Ws[16][68];
    const int m0 = blockIdx.x * 64, n0 = blockIdx.y * 64;
    const int tid = threadIdx.x, ty = tid >> 4, tx = tid & 15;
    float acc[4][4];
#pragma unroll
    for (int i = 0; i < 4; i++)
#pragma unroll
        for (int j = 0; j < 4; j++) acc[i][j] = 0.f;

    for (int k0 = 0; k0 < KD; k0 += 16) {
        {
            int m = tid >> 2, kk = (tid & 3) * 4;
            float4 av = *(const float4*)(A + (long)(m0 + m) * KD + k0 + kk);
            As[kk][m] = av.x; As[kk + 1][m] = av.y; As[kk + 2][m] = av.z; As[kk + 3][m] = av.w;
        }
        {
            int kk = tid >> 4, n = (tid & 15) * 4;
            *(float4*)&Ws[kk][n] = *(const float4*)(W + (long)(k0 + kk) * NC + n0 + n);
        }
        __syncthreads();
#pragma unroll
        for (int kk = 0; kk < 16; kk++) {
            float av[4], wv[4];
            *(float4*)av = *(const float4*)&As[kk][ty * 4];
            *(float4*)wv = *(const float4*)&Ws[kk][tx * 4];
#pragma unroll
            for (int i = 0; i < 4; i++)
#pragma unroll
                for (int j = 0; j < 4; j++) acc[i][j] = fmaf(av[i], wv[j], acc[i][j]);
        }
        __syncthreads();
    }
#pragma unroll
    for (int i = 0; i < 4; i++) {
        int m = m0 + ty * 4 + i;
#pragma unroll
        for (int j = 0; j < 4; j++) {
            int n = n0 + tx * 4 + j;
            float v = acc[i][j] + bias[n];
            if (act) {
                float u = v;
                v = 0.5f * u * (1.f + tanhf(0.7978845608028654f * (u + 0.044715f * u * u * u)));
            }
            if (resid) v += resid[(long)m * NC + n];
            C[(long)m * NC + n] = v;
        }
    }
}

// ---------------- attention: one block per (b, h). S=64, hd=32, causal.
__global__ __launch_bounds__(256) void k_attn(
    const float* __restrict__ qkv, float* __restrict__ o)
{
    int b = blockIdx.x >> 2, h = blockIdx.x & 3;
    __shared__ float q[64][33], k[64][33], v[64][33];
    __shared__ float sc[64][65];
    int tid = threadIdx.x;
#pragma unroll
    for (int it = 0; it < 8; it++) {
        int idx = it * 256 + tid; int s = idx >> 5, d = idx & 31;
        const float* base = qkv + (long)(b * 64 + s) * 384 + h * 32 + d;
        q[s][d] = base[0]; k[s][d] = base[128]; v[s][d] = base[256];
    }
    __syncthreads();
    {
        int sq = tid >> 2, sk0 = (tid & 3) * 16;
        for (int j = 0; j < 16; j++) {
            int sk = sk0 + j;
            float acc = 0.f;
#pragma unroll
            for (int d = 0; d < 32; d++) acc = fmaf(q[sq][d], k[sk][d], acc);
            sc[sq][sk] = (sk <= sq) ? acc * 0.17677669529663687f : -3.0e38f;
        }
    }
    __syncthreads();
    if (tid < 64) {
        float m = -3.0e38f;
        for (int j = 0; j < 64; j++) m = fmaxf(m, sc[tid][j]);
        float s = 0.f;
        for (int j = 0; j < 64; j++) { float e = __expf(sc[tid][j] - m); sc[tid][j] = e; s += e; }
        float inv = 1.f / s;
        for (int j = 0; j < 64; j++) sc[tid][j] *= inv;
    }
    __syncthreads();
#pragma unroll
    for (int it = 0; it < 8; it++) {
        int idx = it * 256 + tid; int s = idx >> 5, d = idx & 31;
        float acc = 0.f;
        for (int sk = 0; sk < 64; sk++) acc = fmaf(sc[s][sk], v[sk][d], acc);
        o[(long)(b * 64 + s) * 128 + h * 32 + d] = acc;
    }
}

// ---------------- head GEMM split-K: A[128 x 8192] @ W[8192 x NC] -> partials
template<int NC>
__global__ __launch_bounds__(256) void k_head(
    const float* __restrict__ A, const float* __restrict__ W,
    float* __restrict__ part)
{
    constexpr int NPT = NC / 16;
    __shared__ float As[16][132];
    __shared__ float Ws[16][NC + 4];
    const int tid = threadIdx.x, ty = tid >> 4, tx = tid & 15;
    float acc[8][NPT];
#pragma unroll
    for (int i = 0; i < 8; i++)
#pragma unroll
        for (int j = 0; j < NPT; j++) acc[i][j] = 0.f;
    const int kbase = blockIdx.x * 64;
    for (int kc = 0; kc < 4; kc++) {
        int k0 = kbase + kc * 16;
        {
            int m = tid >> 1, kk = (tid & 1) * 8;
            const float* ap = A + (long)m * 8192 + k0 + kk;
            float4 a0 = *(const float4*)ap;
            float4 a1 = *(const float4*)(ap + 4);
            As[kk + 0][m] = a0.x; As[kk + 1][m] = a0.y; As[kk + 2][m] = a0.z; As[kk + 3][m] = a0.w;
            As[kk + 4][m] = a1.x; As[kk + 5][m] = a1.y; As[kk + 6][m] = a1.z; As[kk + 7][m] = a1.w;
        }
        for (int e = tid; e < 16 * NC; e += 256) {
            int kk = e / NC, n = e - kk * NC;
            Ws[kk][n] = W[(long)(k0 + kk) * NC + n];
        }
        __syncthreads();
#pragma unroll
        for (int kk = 0; kk < 16; kk++) {
            float av[8];
            *(float4*)av       = *(const float4*)&As[kk][ty * 8];
            *(float4*)(av + 4) = *(const float4*)&As[kk][ty * 8 + 4];
#pragma unroll
            for (int j = 0; j < NPT; j++) {
                float w = Ws[kk][tx * NPT + j];
#pragma unroll
                for (int i = 0; i < 8; i++) acc[i][j] = fmaf(av[i], w, acc[i][j]);
            }
        }
        __syncthreads();
    }
    float* pp = part + (long)blockIdx.x * (128 * NC);
#pragma unroll
    for (int i = 0; i < 8; i++)
#pragma unroll
        for (int j = 0; j < NPT; j++)
            pp[(ty * 8 + i) * NC + tx * NPT + j] = acc[i][j];
}

__global__ __launch_bounds__(256) void k_redhead(
    const float* __restrict__ part, const float* __restrict__ bias,
    float* __restrict__ out, int MN, int NC)
{
    int idx = blockIdx.x * 256 + threadIdx.x;
    if (idx >= MN) return;
    float s = bias[idx % NC];
    for (int b = 0; b < KSPLIT; b++) s += part[(long)b * MN + idx];
    out[idx] = s;
}

__global__ __launch_bounds__(256) void k_l2norm(float* __restrict__ qe)
{
    int row = blockIdx.x * 4 + (threadIdx.x >> 6);
    int lane = threadIdx.x & 63;
    float v0 = qe[row * 128 + lane], v1 = qe[row * 128 + 64 + lane];
    float ss = v0 * v0 + v1 * v1;
#pragma unroll
    for (int o = 32; o; o >>= 1) ss += __shfl_down(ss, o);
    ss = __shfl(ss, 0);
    float inv = 1.f / fmaxf(sqrtf(ss), 1e-12f);
    qe[row * 128 + lane] = v0 * inv;
    qe[row * 128 + 64 + lane] = v1 * inv;
}

// ---------------- build query B-fragments (hi/lo bf16, frag-ordered)
// frag element (ks,t,lane,j): B[k=quad*8+j][n=lane&15] of tile (ks, t)
__global__ __launch_bounds__(256) void k_qprep(
    const float* __restrict__ qe, short* __restrict__ qfh, short* __restrict__ qfl)
{
    int idx = blockIdx.x * 256 + threadIdx.x;     // 16384
    int j = idx & 7, lane = (idx >> 3) & 63, t = (idx >> 9) & 7, ks = idx >> 12;
    int n = t * 16 + (lane & 15);
    int d = ks * 32 + (lane >> 4) * 8 + j;
    float x = qe[n * 128 + d];
    short h = f2bf(x);
    qfh[idx] = h;
    qfl[idx] = f2bf(x - bf2f(h));
}

// ---------------- sim via MFMA (hi/lo bf16 split, 3 terms) + per-block top-16
// 512 thr = 8 waves: wave = (kg = w>>2 keys-half, qg = w&3 query-quarter)
// pass = 64 keys staged hi/lo in LDS; queries resident in registers.
__global__ __launch_bounds__(512, 2) void k_sim2(
    const float* __restrict__ keys, const short* __restrict__ qfh,
    const short* __restrict__ qfl,
    float* __restrict__ cval, int* __restrict__ cidx)
{
    __shared__ short afh[8192];     // 16 KB: A-frags hi, 4 mtiles x 4 ksteps
    __shared__ short afl[8192];     // 16 KB: A-frags lo
    __shared__ float sim[8192];     // 32 KB: 8 waves x 32k x 32q
    const int tid = threadIdx.x;
    const int w = tid >> 6, lane = tid & 63;
    const int quad = lane >> 4, l15 = lane & 15;
    const int kg = w >> 2, qg = w & 3;

    // query B-fragments in registers (hi+lo): 4 ksteps x 2 ntiles
    short8 bh[4][2], bl[4][2];
    {
        const short8* qfh8 = (const short8*)qfh;
        const short8* qfl8 = (const short8*)qfl;
#pragma unroll
        for (int ks = 0; ks < 4; ks++)
#pragma unroll
            for (int tt = 0; tt < 2; tt++) {
                int f = (ks * 8 + qg * 2 + tt) * 64 + lane;
                bh[ks][tt] = qfh8[f];
                bl[ks][tt] = qfl8[f];
            }
    }

    float tv[16]; int tix[16];
#pragma unroll
    for (int j = 0; j < 16; j++) { tv[j] = -3.0e38f; tix[j] = 0; }
    float runmin = -3.0e38f;

    // staging role of this thread: row r_loc (0..63), d-window d0..d0+15
    const int r_loc = tid >> 3;
    const int d0 = (tid & 7) * 16;
    const int mt = r_loc >> 4, rr = r_loc & 15;

    float4 R[4];
    int p = blockIdx.x;
    {
        int gk = p * 64 + r_loc;
#pragma unroll
        for (int c = 0; c < 4; c++) {
            int d = d0 + c * 4;
            R[c] = (gk < NKEY) ? *(const float4*)(keys + (long)gk * 128 + d)
                               : make_float4(0.f, 0.f, 0.f, 0.f);
        }
    }

    for (; p < NPASS; p += SB) {
        __syncthreads();            // prior pass frag reads complete
        // convert current pass keys -> hi/lo frags in LDS
#pragma unroll
        for (int c = 0; c < 4; c++) {
            int d = d0 + c * 4;
            int ks = d >> 5, qd = (d & 31) >> 3, j = d & 7;
            int slot = (((mt * 4 + ks) * 64) + qd * 16 + rr) * 8 + j;
            float e0 = R[c].x, e1 = R[c].y, e2 = R[c].z, e3 = R[c].w;
            short h0 = f2bf(e0), h1 = f2bf(e1), h2 = f2bf(e2), h3 = f2bf(e3);
            short l0 = f2bf(e0 - bf2f(h0)), l1 = f2bf(e1 - bf2f(h1));
            short l2 = f2bf(e2 - bf2f(h2)), l3 = f2bf(e3 - bf2f(h3));
            int2 hp, lp;
            hp.x = (h0 & 0xFFFF) | ((int)h1 << 16);
            hp.y = (h2 & 0xFFFF) | ((int)h3 << 16);
            lp.x = (l0 & 0xFFFF) | ((int)l1 << 16);
            lp.y = (l2 & 0xFFFF) | ((int)l3 << 16);
            *(int2*)&afh[slot] = hp;
            *(int2*)&afl[slot] = lp;
        }
        {   // prefetch next pass
            int pn = p + SB;
            if (pn < NPASS) {
                int gk = pn * 64 + r_loc;
#pragma unroll
                for (int c = 0; c < 4; c++) {
                    int d = d0 + c * 4;
                    R[c] = (gk < NKEY) ? *(const float4*)(keys + (long)gk * 128 + d)
                                       : make_float4(0.f, 0.f, 0.f, 0.f);
                }
            }
        }
        __syncthreads();

        f32x4 acc[2][2];
#pragma unroll
        for (int m = 0; m < 2; m++)
#pragma unroll
            for (int tt = 0; tt < 2; tt++) acc[m][tt] = (f32x4){0.f, 0.f, 0.f, 0.f};

        const short8* ah8 = (const short8*)afh;
        const short8* al8 = (const short8*)afl;
#pragma unroll
        for (int ks = 0; ks < 4; ks++) {
            short8 a_h[2], a_l[2];
#pragma unroll
            for (int m = 0; m < 2; m++) {
                int f = ((kg * 2 + m) * 4 + ks) * 64 + lane;
                a_h[m] = ah8[f]; a_l[m] = al8[f];
            }
#pragma unroll
            for (int m = 0; m < 2; m++)
#pragma unroll
                for (int tt = 0; tt < 2; tt++) {
                    acc[m][tt] = __builtin_amdgcn_mfma_f32_16x16x32_bf16(a_h[m], bh[ks][tt], acc[m][tt], 0, 0, 0);
                    acc[m][tt] = __builtin_amdgcn_mfma_f32_16x16x32_bf16(a_h[m], bl[ks][tt], acc[m][tt], 0, 0, 0);
                    acc[m][tt] = __builtin_amdgcn_mfma_f32_16x16x32_bf16(a_l[m], bh[ks][tt], acc[m][tt], 0, 0, 0);
                }
        }
        // write wave-local sim tile [32 keys][32 queries]
        float* sw = sim + w * 1024;
#pragma unroll
        for (int m = 0; m < 2; m++)
#pragma unroll
            for (int tt = 0; tt < 2; tt++)
#pragma unroll
                for (int r = 0; r < 4; r++)
                    sw[(m * 16 + quad * 4 + r) * 32 + tt * 16 + l15] = acc[m][tt][r];
        // scan: lanes 0..31 own one query each (wave-local, no barrier)
        if (lane < 32) {
            int kbase = p * 64 + kg * 32;
            for (int kk = 0; kk < 32; kk++) {
                int gk2 = kbase + kk;
                float v = sw[kk * 32 + lane];
                if (gk2 < NKEY && v > runmin) {
                    int slot = 0; float mv = tv[0];
#pragma unroll
                    for (int j = 1; j < 16; j++) if (tv[j] < mv) { mv = tv[j]; slot = j; }
                    tv[slot] = v; tix[slot] = gk2;
                    runmin = tv[0];
#pragma unroll
                    for (int j = 1; j < 16; j++) runmin = fminf(runmin, tv[j]);
                }
            }
        }
    }
    // merge the two kg-halves per query via scratch (reuse afh/afl)
    __syncthreads();
    float* scv = (float*)afh;    // 128 q x 32 entries
    int*   sci = (int*)afl;
    if (lane < 32) {
        int q = qg * 32 + lane;
#pragma unroll
        for (int j = 0; j < 16; j++) {
            scv[q * 32 + kg * 16 + j] = tv[j];
            sci[q * 32 + kg * 16 + j] = tix[j];
        }
    }
    __syncthreads();
    if (tid < 128) {
        float fv[16]; int fi[16];
#pragma unroll
        for (int j = 0; j < 16; j++) { fv[j] = -3.0e38f; fi[j] = 0; }
        float rm = -3.0e38f;
        for (int e = 0; e < 32; e++) {
            float v = scv[tid * 32 + e];
            if (v > rm) {
                int slot = 0; float mv = fv[0];
#pragma unroll
                for (int j = 1; j < 16; j++) if (fv[j] < mv) { mv = fv[j]; slot = j; }
                fv[slot] = v; fi[slot] = sci[tid * 32 + e];
                rm = fv[0];
#pragma unroll
                for (int j = 1; j < 16; j++) rm = fminf(rm, fv[j]);
            }
        }
        int ob = (blockIdx.x * 128 + tid) * 16;
#pragma unroll
        for (int j = 0; j < 16; j++) { cval[ob + j] = fv[j]; cidx[ob + j] = fi[j]; }
    }
}

// ---------------- merge candidates, softmax, gather memory_values, fuse
__global__ __launch_bounds__(256) void k_merge(
    const float* __restrict__ cval, const int* __restrict__ cidx,
    const float* __restrict__ base, const float* __restrict__ mvals,
    const float* __restrict__ fw, float* __restrict__ out)
{
    __shared__ float sv[NCAND];
    __shared__ int   si[NCAND];
    __shared__ float wv[4]; __shared__ int wi[4];
    __shared__ float tvs[16]; __shared__ int tis[16];
    const int q = blockIdx.x, tid = threadIdx.x;
    for (int i = tid; i < NCAND; i += 256) {
        sv[i] = cval[(i >> 4) * 2048 + q * 16 + (i & 15)];
        si[i] = cidx[(i >> 4) * 2048 + q * 16 + (i & 15)];
    }
    __syncthreads();
    for (int r = 0; r < 16; r++) {
        float bv = -3.0e38f; int bp = -1;
        for (int i = tid; i < NCAND; i += 256) {
            float v = sv[i];
            if (v > bv) { bv = v; bp = i; }
        }
#pragma unroll
        for (int o = 32; o; o >>= 1) {
            float ov = __shfl_down(bv, o); int op = __shfl_down(bp, o);
            if (ov > bv) { bv = ov; bp = op; }
        }
        if ((tid & 63) == 0) { wv[tid >> 6] = bv; wi[tid >> 6] = bp; }
        __syncthreads();
        if (tid == 0) {
            float b2 = wv[0]; int p2 = wi[0];
            for (int ww = 1; ww < 4; ww++) if (wv[ww] > b2) { b2 = wv[ww]; p2 = wi[ww]; }
            tvs[r] = b2; tis[r] = si[p2]; sv[p2] = -3.0e38f;
        }
        __syncthreads();
    }
    float alpha = 1.f / (1.f + expf(-fw[0]));
    if (tid < PDIM) {
        float m = tvs[0];
#pragma unroll
        for (int r = 1; r < 16; r++) m = fmaxf(m, tvs[r]);
        float wgt[16]; float s = 0.f;
#pragma unroll
        for (int r = 0; r < 16; r++) { wgt[r] = expf(tvs[r] - m); s += wgt[r]; }
        float inv = 1.f / s;
        float ret = 0.f;
#pragma unroll
        for (int r = 0; r < 16; r++) ret += wgt[r] * inv * mvals[(long)tis[r] * PDIM + tid];
        out[q * PDIM + tid] = alpha * base[q * PDIM + tid] + (1.f - alpha) * ret;
    }
}

// ---------------- launch
extern "C" void kernel_launch(void* const* d_in, const int* in_sizes, int n_in,
                              void* d_out, int out_size, void* d_ws, size_t ws_size,
                              hipStream_t stream)
{
    const float* x      = (const float*)d_in[0];
    const float* keys   = (const float*)d_in[1];
    const float* mvals  = (const float*)d_in[2];
    const float* wpe    = (const float*)d_in[3];
    const float* w_in   = (const float*)d_in[4];
    const float* b_in   = (const float*)d_in[5];
    const float* ln1_g  = (const float*)d_in[6];
    const float* ln1_b  = (const float*)d_in[7];
    const float* attn_w = (const float*)d_in[8];
    const float* attn_b = (const float*)d_in[9];
    const float* attn_pw= (const float*)d_in[10];
    const float* attn_pb= (const float*)d_in[11];
    const float* ln2_g  = (const float*)d_in[12];
    const float* ln2_b  = (const float*)d_in[13];
    const float* fc_w   = (const float*)d_in[14];
    const float* fc_b   = (const float*)d_in[15];
    const float* mlp_pw = (const float*)d_in[16];
    const float* mlp_pb = (const float*)d_in[17];
    const float* lnf_g  = (const float*)d_in[18];
    const float* lnf_b  = (const float*)d_in[19];
    const float* w_out  = (const float*)d_in[20];
    const float* b_out  = (const float*)d_in[21];
    const float* ret_w1 = (const float*)d_in[22];
    const float* ret_b1 = (const float*)d_in[23];
    const float* ret_w2 = (const float*)d_in[24];
    const float* ret_b2 = (const float*)d_in[25];
    const float* fw     = (const float*)d_in[26];
    float* out = (float*)d_out;

    float* ws   = (float*)d_ws;
    float* h    = ws + 0;            // 1048576
    float* bufA = ws + 1048576;      // 1048576
    float* bufB = ws + 2097152;      // 4194304
    float* bufO = ws + 6291456;      // 1048576
    float* part = ws + 7340032;      // 2359296
    float* base = ws + 9699328;      // 18432
    float* qe   = ws + 9717760;      // 16384
    short* qfh  = (short*)(ws + 9734144);   // 16384 shorts
    short* qfl  = (short*)(ws + 9742336);   // 16384 shorts
    float* cval = ws + 9750528;      // 524288
    int*   cidx = (int*)(ws + 10274816);    // 524288

    k_embed<<<4096, 256, 0, stream>>>(x, w_in, b_in, wpe, h);
    for (int l = 0; l < 3; l++) {
        k_ln<<<2048, 256, 0, stream>>>(h, ln1_g + l * 128, ln1_b + l * 128, bufA);
        k_gemm<128><<<dim3(128, 6), 256, 0, stream>>>(bufA, attn_w + l * 49152,
            attn_b + l * 384, nullptr, bufB, 384, 0);
        k_attn<<<512, 256, 0, stream>>>(bufB, bufO);
        k_gemm<128><<<dim3(128, 2), 256, 0, stream>>>(bufO, attn_pw + l * 16384,
            attn_pb + l * 128, h, h, 128, 0);
        k_ln<<<2048, 256, 0, stream>>>(h, ln2_g + l * 128, ln2_b + l * 128, bufA);
        k_gemm<128><<<dim3(128, 8), 256, 0, stream>>>(bufA, fc_w + l * 65536,
            fc_b + l * 512, nullptr, bufB, 512, 1);
        k_gemm<512><<<dim3(128, 2), 256, 0, stream>>>(bufB, mlp_pw + l * 65536,
            mlp_pb + l * 128, h, h, 128, 0);
    }
    k_ln<<<2048, 256, 0, stream>>>(h, lnf_g, lnf_b, bufA);
    k_head<144><<<KSPLIT, 256, 0, stream>>>(bufA, w_out, part);
    k_redhead<<<72, 256, 0, stream>>>(part, b_out, base, 128 * 144, 144);

    k_embed<<<4096, 256, 0, stream>>>(x, ret_w1, ret_b1, nullptr, bufO);
    k_head<128><<<KSPLIT, 256, 0, stream>>>(bufO, ret_w2, part);
    k_redhead<<<64, 256, 0, stream>>>(part, ret_b2, qe, 128 * 128, 128);
    k_l2norm<<<32, 256, 0, stream>>>(qe);

    k_qprep<<<64, 256, 0, stream>>>(qe, qfh, qfl);
    k_sim2<<<SB, 512, 0, stream>>>(keys, qfh, qfl, cval, cidx);
    k_merge<<<128, 256, 0, stream>>>(cval, cidx, base, mvals, fw, out);
}

// Round 3
// 1237.288 us; speedup vs baseline: 1.6145x; 1.0626x over previous
//
#include <hip/hip_runtime.h>
#include <math.h>

#define TOK   8192
#define DM    128
#define NKEY  500000
#define PDIM  144
#define KSPLIT 128

#define SB     512                 // sim grid (blocks)
#define NPASS  7813                // ceil(500000 / 64)
#define NCAND  (SB * 16)           // 8192 candidates per query

typedef __attribute__((ext_vector_type(8))) short short8;
typedef __attribute__((ext_vector_type(4))) float f32x4;

__device__ __forceinline__ short f2bf(float x) {
    union { float f; unsigned u; } v; v.f = x;
    unsigned r = v.u + 0x7FFFu + ((v.u >> 16) & 1u);
    return (short)(r >> 16);
}
__device__ __forceinline__ float bf2f(short h) {
    union { float f; unsigned u; } v;
    v.u = ((unsigned)(unsigned short)h) << 16;
    return v.f;
}

// sorted-descending top-16 insert, all static indices (registers only)
__device__ __forceinline__ void ins16(float v, int id, float* tv, int* tix) {
#pragma unroll
    for (int j = 15; j > 0; j--) {
        bool up = v > tv[j];
        bool sh = v > tv[j - 1];
        float nv = sh ? tv[j - 1] : v;
        int   ni = sh ? tix[j - 1] : id;
        tv[j]  = up ? nv : tv[j];
        tix[j] = up ? ni : tix[j];
    }
    if (v > tv[0]) { tv[0] = v; tix[0] = id; }
}

// ---------------- both embeds in one kernel
__global__ __launch_bounds__(256) void k_embed2(
    const float* __restrict__ x, const float* __restrict__ w,
    const float* __restrict__ b, const float* __restrict__ wpe,
    float* __restrict__ out, const float* __restrict__ rw,
    const float* __restrict__ rb, float* __restrict__ rout)
{
    int bid = blockIdx.x;
    if (bid < 4096) {
        int idx = bid * 256 + threadIdx.x;
        int t = idx >> 7, d = idx & 127;
        float acc = b[d] + wpe[(t & 63) * DM + d];
        const float* xr = x + t * 6;
#pragma unroll
        for (int i = 0; i < 6; i++) acc = fmaf(xr[i], w[i * DM + d], acc);
        out[idx] = acc;
    } else {
        int idx = (bid - 4096) * 256 + threadIdx.x;
        int t = idx >> 7, d = idx & 127;
        float acc = rb[d];
        const float* xr = x + t * 6;
#pragma unroll
        for (int i = 0; i < 6; i++) acc = fmaf(xr[i], rw[i * DM + d], acc);
        rout[idx] = acc;
    }
}

// ---------------- layernorm (only for lnf now)
__global__ __launch_bounds__(256) void k_ln(
    const float* __restrict__ in, const float* __restrict__ g,
    const float* __restrict__ b, float* __restrict__ out)
{
    int row = blockIdx.x * 4 + (threadIdx.x >> 6);
    int lane = threadIdx.x & 63;
    const float* r = in + row * DM;
    float v0 = r[lane], v1 = r[lane + 64];
    float s = v0 + v1, ss = v0 * v0 + v1 * v1;
#pragma unroll
    for (int o = 32; o; o >>= 1) { s += __shfl_down(s, o); ss += __shfl_down(ss, o); }
    s = __shfl(s, 0); ss = __shfl(ss, 0);
    float mean = s * (1.f / 128.f);
    float var = ss * (1.f / 128.f) - mean * mean;
    float rstd = rsqrtf(var + 1e-5f);
    out[row * DM + lane]      = (v0 - mean) * rstd * g[lane]      + b[lane];
    out[row * DM + lane + 64] = (v1 - mean) * rstd * g[lane + 64] + b[lane + 64];
}

// ---------------- LN-fused GEMM, K=128: C = LN(A) @ W + bias, optional gelu
template<int ACT>
__global__ __launch_bounds__(256) void k_gemmln(
    const float* __restrict__ A, const float* __restrict__ g,
    const float* __restrict__ bln, const float* __restrict__ W,
    const float* __restrict__ bias, float* __restrict__ C, int NC)
{
    __shared__ float As[128][68];   // [k][m] normalized
    __shared__ float Ws[16][68];
    const int tid = threadIdx.x;
    const int m0 = blockIdx.x * 64, n0 = blockIdx.y * 64;
    {
        int row = tid >> 2, part = tid & 3;
        const float* ar = A + (long)(m0 + row) * 128 + part * 32;
        float v[32];
        float s = 0.f, ss = 0.f;
#pragma unroll
        for (int i2 = 0; i2 < 8; i2++) {
            float4 t = *(const float4*)(ar + i2 * 4);
            v[i2 * 4 + 0] = t.x; v[i2 * 4 + 1] = t.y;
            v[i2 * 4 + 2] = t.z; v[i2 * 4 + 3] = t.w;
            s += t.x + t.y + t.z + t.w;
            ss += t.x * t.x + t.y * t.y + t.z * t.z + t.w * t.w;
        }
        s += __shfl_xor(s, 1); s += __shfl_xor(s, 2);
        ss += __shfl_xor(ss, 1); ss += __shfl_xor(ss, 2);
        float mean = s * (1.f / 128.f);
        float rstd = rsqrtf(ss * (1.f / 128.f) - mean * mean + 1e-5f);
#pragma unroll
        for (int i = 0; i < 32; i++) {
            int d = part * 32 + i;
            As[d][row] = (v[i] - mean) * rstd * g[d] + bln[d];
        }
    }
    const int ty = tid >> 4, tx = tid & 15;
    float acc[4][4];
#pragma unroll
    for (int i = 0; i < 4; i++)
#pragma unroll
        for (int j = 0; j < 4; j++) acc[i][j] = 0.f;
    __syncthreads();
    for (int k0 = 0; k0 < 128; k0 += 16) {
        {
            int kk = tid >> 4, n = (tid & 15) * 4;
            *(float4*)&Ws[kk][n] = *(const float4*)(W + (long)(k0 + kk) * NC + n0 + n);
        }
        __syncthreads();
#pragma unroll
        for (int kk = 0; kk < 16; kk++) {
            float av[4], wv[4];
            *(float4*)av = *(const float4*)&As[k0 + kk][ty * 4];
            *(float4*)wv = *(const float4*)&Ws[kk][tx * 4];
#pragma unroll
            for (int i = 0; i < 4; i++)
#pragma unroll
                for (int j = 0; j < 4; j++) acc[i][j] = fmaf(av[i], wv[j], acc[i][j]);
        }
        __syncthreads();
    }
#pragma unroll
    for (int i = 0; i < 4; i++) {
        int m = m0 + ty * 4 + i;
#pragma unroll
        for (int j = 0; j < 4; j++) {
            int n = n0 + tx * 4 + j;
            float u = acc[i][j] + bias[n];
            if (ACT) {
                float z = 0.7978845608028654f * (u + 0.044715f * u * u * u);
                z = fminf(fmaxf(z, -15.f), 15.f);
                float t = __expf(2.f * z);
                u = 0.5f * u * (1.f + (t - 1.f) / (t + 1.f));
            }
            C[(long)m * NC + n] = u;
        }
    }
}

// ---------------- plain GEMM (proj / mlp): C = A @ W + bias (+resid)
template<int KD>
__global__ __launch_bounds__(256) void k_gemm(
    const float* __restrict__ A, const float* __restrict__ W,
    const float* __restrict__ bias, const float* __restrict__ resid,
    float* __restrict__ C, int NC)
{
    __shared__ float As[16][68];
    __shared__ float Ws[16][68];
    const int m0 = blockIdx.x * 64, n0 = blockIdx.y * 64;
    const int tid = threadIdx.x, ty = tid >> 4, tx = tid & 15;
    float acc[4][4];
#pragma unroll
    for (int i = 0; i < 4; i++)
#pragma unroll
        for (int j = 0; j < 4; j++) acc[i][j] = 0.f;
    for (int k0 = 0; k0 < KD; k0 += 16) {
        {
            int m = tid >> 2, kk = (tid & 3) * 4;
            float4 av = *(const float4*)(A + (long)(m0 + m) * KD + k0 + kk);
            As[kk][m] = av.x; As[kk + 1][m] = av.y; As[kk + 2][m] = av.z; As[kk + 3][m] = av.w;
        }
        {
            int kk = tid >> 4, n = (tid & 15) * 4;
            *(float4*)&Ws[kk][n] = *(const float4*)(W + (long)(k0 + kk) * NC + n0 + n);
        }
        __syncthreads();
#pragma unroll
        for (int kk = 0; kk < 16; kk++) {
            float av[4], wv[4];
            *(float4*)av = *(const float4*)&As[kk][ty * 4];
            *(float4*)wv = *(const float4*)&Ws[kk][tx * 4];
#pragma unroll
            for (int i = 0; i < 4; i++)
#pragma unroll
                for (int j = 0; j < 4; j++) acc[i][j] = fmaf(av[i], wv[j], acc[i][j]);
        }
        __syncthreads();
    }
#pragma unroll
    for (int i = 0; i < 4; i++) {
        int m = m0 + ty * 4 + i;
#pragma unroll
        for (int j = 0; j < 4; j++) {
            int n = n0 + tx * 4 + j;
            float u = acc[i][j] + bias[n];
            if (resid) u += resid[(long)m * NC + n];
            C[(long)m * NC + n] = u;
        }
    }
}

// ---------------- attention: one block per (b, h). S=64, hd=32, causal.
__global__ __launch_bounds__(256) void k_attn(
    const float* __restrict__ qkv, float* __restrict__ o)
{
    int b = blockIdx.x >> 2, h = blockIdx.x & 3;
    __shared__ float q[64][33], k[64][33], v[64][33];
    __shared__ float att[64][65];
    int tid = threadIdx.x;
#pragma unroll
    for (int it = 0; it < 8; it++) {
        int idx = it * 256 + tid; int s = idx >> 5, d = idx & 31;
        const float* base = qkv + (long)(b * 64 + s) * 384 + h * 32 + d;
        q[s][d] = base[0]; k[s][d] = base[128]; v[s][d] = base[256];
    }
    __syncthreads();
    {
        int sq = tid >> 2, sk0 = (tid & 3) * 16;
        float e[16]; float mx = -3.0e38f;
#pragma unroll
        for (int j = 0; j < 16; j++) {
            int sk = sk0 + j;
            float a = 0.f;
#pragma unroll
            for (int d = 0; d < 32; d++) a = fmaf(q[sq][d], k[sk][d], a);
            a = (sk <= sq) ? a * 0.17677669529663687f : -3.0e38f;
            e[j] = a; mx = fmaxf(mx, a);
        }
        mx = fmaxf(mx, __shfl_xor(mx, 1)); mx = fmaxf(mx, __shfl_xor(mx, 2));
        float s = 0.f;
#pragma unroll
        for (int j = 0; j < 16; j++) { e[j] = __expf(e[j] - mx); s += e[j]; }
        s += __shfl_xor(s, 1); s += __shfl_xor(s, 2);
        float inv = 1.f / s;
#pragma unroll
        for (int j = 0; j < 16; j++) att[sq][sk0 + j] = e[j] * inv;
    }
    __syncthreads();
#pragma unroll
    for (int it = 0; it < 8; it++) {
        int idx = it * 256 + tid; int s = idx >> 5, d = idx & 31;
        float acc = 0.f;
        for (int sk = 0; sk < 64; sk++) acc = fmaf(att[s][sk], v[sk][d], acc);
        o[(long)(b * 64 + s) * 128 + h * 32 + d] = acc;
    }
}

// ---------------- head GEMM split-K
template<int NC>
__global__ __launch_bounds__(256) void k_head(
    const float* __restrict__ A, const float* __restrict__ W,
    float* __restrict__ part)
{
    constexpr int NPT = NC / 16;
    __shared__ float As[16][132];
    __shared__ float Ws[16][NC + 4];
    const int tid = threadIdx.x, ty = tid >> 4, tx = tid & 15;
    float acc[8][NPT];
#pragma unroll
    for (int i = 0; i < 8; i++)
#pragma unroll
        for (int j = 0; j < NPT; j++) acc[i][j] = 0.f;
    const int kbase = blockIdx.x * 64;
    for (int kc = 0; kc < 4; kc++) {
        int k0 = kbase + kc * 16;
        {
            int m = tid >> 1, kk = (tid & 1) * 8;
            const float* ap = A + (long)m * 8192 + k0 + kk;
            float4 a0 = *(const float4*)ap;
            float4 a1 = *(const float4*)(ap + 4);
            As[kk + 0][m] = a0.x; As[kk + 1][m] = a0.y; As[kk + 2][m] = a0.z; As[kk + 3][m] = a0.w;
            As[kk + 4][m] = a1.x; As[kk + 5][m] = a1.y; As[kk + 6][m] = a1.z; As[kk + 7][m] = a1.w;
        }
        for (int e = tid; e < 16 * NC; e += 256) {
            int kk = e / NC, n = e - kk * NC;
            Ws[kk][n] = W[(long)(k0 + kk) * NC + n];
        }
        __syncthreads();
#pragma unroll
        for (int kk = 0; kk < 16; kk++) {
            float av[8];
            *(float4*)av       = *(const float4*)&As[kk][ty * 8];
            *(float4*)(av + 4) = *(const float4*)&As[kk][ty * 8 + 4];
#pragma unroll
            for (int j = 0; j < NPT; j++) {
                float wv = Ws[kk][tx * NPT + j];
#pragma unroll
                for (int i = 0; i < 8; i++) acc[i][j] = fmaf(av[i], wv, acc[i][j]);
            }
        }
        __syncthreads();
    }
    float* pp = part + (long)blockIdx.x * (128 * NC);
#pragma unroll
    for (int i = 0; i < 8; i++)
#pragma unroll
        for (int j = 0; j < NPT; j++)
            pp[(ty * 8 + i) * NC + tx * NPT + j] = acc[i][j];
}

__global__ __launch_bounds__(256) void k_redhead(
    const float* __restrict__ part, const float* __restrict__ bias,
    float* __restrict__ out, int MN, int NC)
{
    int idx = blockIdx.x * 256 + threadIdx.x;
    if (idx >= MN) return;
    float s = bias[idx % NC];
    for (int b = 0; b < KSPLIT; b++) s += part[(long)b * MN + idx];
    out[idx] = s;
}

// qe reduction + per-row sum of squares (for l2 normalize)
__global__ __launch_bounds__(256) void k_redhead_qe(
    const float* __restrict__ part, const float* __restrict__ bias,
    float* __restrict__ out, float* __restrict__ ssq)
{
    __shared__ float hsum[4];
    int tid = threadIdx.x;
    int idx = blockIdx.x * 256 + tid;
    float s = bias[idx & 127];
    for (int b = 0; b < KSPLIT; b++) s += part[(long)b * 16384 + idx];
    out[idx] = s;
    float sq = s * s;
#pragma unroll
    for (int o = 32; o; o >>= 1) sq += __shfl_down(sq, o);
    if ((tid & 63) == 0) hsum[tid >> 6] = sq;
    __syncthreads();
    if (tid == 0)   ssq[blockIdx.x * 2]     = hsum[0] + hsum[1];
    if (tid == 128) ssq[blockIdx.x * 2 + 1] = hsum[2] + hsum[3];
}

// ---------------- build L2-normalized query B-fragments (hi/lo bf16)
__global__ __launch_bounds__(256) void k_qprep(
    const float* __restrict__ qe, const float* __restrict__ ssq,
    short* __restrict__ qfh, short* __restrict__ qfl)
{
    int idx = blockIdx.x * 256 + threadIdx.x;     // 16384
    int j = idx & 7, lane = (idx >> 3) & 63, t = (idx >> 9) & 7, ks = idx >> 12;
    int n = t * 16 + (lane & 15);
    int d = ks * 32 + (lane >> 4) * 8 + j;
    float inv = 1.f / fmaxf(sqrtf(ssq[n]), 1e-12f);
    float x = qe[n * 128 + d] * inv;
    short h = f2bf(x);
    qfh[idx] = h;
    qfl[idx] = f2bf(x - bf2f(h));
}

__device__ __forceinline__ void cvt8(float4 a, float4 b, int4& hi, int4& lo) {
    float e[8] = {a.x, a.y, a.z, a.w, b.x, b.y, b.z, b.w};
    int h[8], l[8];
#pragma unroll
    for (int i = 0; i < 8; i++) {
        short hh = f2bf(e[i]);
        h[i] = (int)hh & 0xFFFF;
        l[i] = (int)f2bf(e[i] - bf2f(hh)) & 0xFFFF;
    }
    hi.x = h[0] | (h[1] << 16); hi.y = h[2] | (h[3] << 16);
    hi.z = h[4] | (h[5] << 16); hi.w = h[6] | (h[7] << 16);
    lo.x = l[0] | (l[1] << 16); lo.y = l[2] | (l[3] << 16);
    lo.z = l[4] | (l[5] << 16); lo.w = l[6] | (l[7] << 16);
}

// ---------------- sim via MFMA hi/lo bf16, register top-16
// 8 waves; wave w owns 16 queries. Lane owns (query = w*16+(lane&15),
// key-quarter = lane>>4). 64 keys per pass staged as frags in LDS.
__global__ __launch_bounds__(512, 2) void k_sim3(
    const float* __restrict__ keys, const short* __restrict__ qfh,
    const short* __restrict__ qfl,
    float* __restrict__ cval, int* __restrict__ cidx)
{
    __shared__ __align__(16) char sm[67584];
    short* afh = (short*)sm;                 // 16 KB
    short* afl = (short*)(sm + 16384);       // 16 KB
    float* simb = (float*)(sm + 32768);      // 8 waves x 64x17 floats

    const int tid = threadIdx.x;
    const int w = tid >> 6, lane = tid & 63;
    const int quad = lane >> 4, l15 = lane & 15;
    const int qg = w;

    short8 bh[4], bl[4];
    {
        const short8* qfh8 = (const short8*)qfh;
        const short8* qfl8 = (const short8*)qfl;
#pragma unroll
        for (int ks = 0; ks < 4; ks++) {
            int f = (ks * 8 + qg) * 64 + lane;
            bh[ks] = qfh8[f]; bl[ks] = qfl8[f];
        }
    }

    float tv[16]; int tix[16];
#pragma unroll
    for (int j = 0; j < 16; j++) { tv[j] = -3.0e38f; tix[j] = 0; }

    // staging role: key r = tid>>3, octet o = tid&7 (d = o*8 and 64+o*8)
    const int r = tid >> 3, o = tid & 7;
    const int mt = r >> 4, rr = r & 15;
    const int L = (o & 3) * 16 + rr;
    const int t8a = mt * 4 + (o >> 2);
    const int t8b = mt * 4 + 2 + (o >> 2);
    short* dha = afh + (t8a * 64 + L) * 8;
    short* dla = afl + (t8a * 64 + L) * 8;
    short* dhb = afh + (t8b * 64 + L) * 8;
    short* dlb = afl + (t8b * 64 + L) * 8;

    const int q_own = l15, kq = quad;
    float* sw = simb + w * 1088;

    float4 R[4];
    int p = blockIdx.x;
    {
        int gk = p * 64 + r;
        const float* kp = keys + (long)gk * 128 + o * 8;
        bool ok = gk < NKEY;
        R[0] = ok ? *(const float4*)kp        : make_float4(0.f,0.f,0.f,0.f);
        R[1] = ok ? *(const float4*)(kp + 4)  : make_float4(0.f,0.f,0.f,0.f);
        R[2] = ok ? *(const float4*)(kp + 64) : make_float4(0.f,0.f,0.f,0.f);
        R[3] = ok ? *(const float4*)(kp + 68) : make_float4(0.f,0.f,0.f,0.f);
    }

    for (; p < NPASS; p += SB) {
        {
            int4 hi, lo;
            cvt8(R[0], R[1], hi, lo);
            *(int4*)dha = hi; *(int4*)dla = lo;
            cvt8(R[2], R[3], hi, lo);
            *(int4*)dhb = hi; *(int4*)dlb = lo;
        }
        {
            int pn = p + SB;
            if (pn < NPASS) {
                int gk = pn * 64 + r;
                const float* kp = keys + (long)gk * 128 + o * 8;
                bool ok = gk < NKEY;
                R[0] = ok ? *(const float4*)kp        : make_float4(0.f,0.f,0.f,0.f);
                R[1] = ok ? *(const float4*)(kp + 4)  : make_float4(0.f,0.f,0.f,0.f);
                R[2] = ok ? *(const float4*)(kp + 64) : make_float4(0.f,0.f,0.f,0.f);
                R[3] = ok ? *(const float4*)(kp + 68) : make_float4(0.f,0.f,0.f,0.f);
            }
        }
        __syncthreads();    // frags ready

        f32x4 acc[4];
#pragma unroll
        for (int m = 0; m < 4; m++) acc[m] = (f32x4){0.f, 0.f, 0.f, 0.f};
        const short8* ah8 = (const short8*)afh;
        const short8* al8 = (const short8*)afl;
#pragma unroll
        for (int ks = 0; ks < 4; ks++) {
            short8 ah[4], al[4];
#pragma unroll
            for (int m = 0; m < 4; m++) {
                int f = (m * 4 + ks) * 64 + lane;
                ah[m] = ah8[f]; al[m] = al8[f];
            }
#pragma unroll
            for (int m = 0; m < 4; m++) {
                acc[m] = __builtin_amdgcn_mfma_f32_16x16x32_bf16(ah[m], bh[ks], acc[m], 0, 0, 0);
                acc[m] = __builtin_amdgcn_mfma_f32_16x16x32_bf16(ah[m], bl[ks], acc[m], 0, 0, 0);
                acc[m] = __builtin_amdgcn_mfma_f32_16x16x32_bf16(al[m], bh[ks], acc[m], 0, 0, 0);
            }
        }
#pragma unroll
        for (int m = 0; m < 4; m++)
#pragma unroll
            for (int r4 = 0; r4 < 4; r4++)
                sw[(m * 16 + quad * 4 + r4) * 17 + l15] = acc[m][r4];
        __syncthreads();    // sim ready (also fences frag buffer reuse)

        int limit = NKEY - p * 64;
        float thr = tv[15];
#pragma unroll
        for (int bb = 0; bb < 2; bb++) {
            float vv[8];
#pragma unroll
            for (int i = 0; i < 8; i++) {
                int kk = kq * 16 + bb * 8 + i;
                float vx = sw[kk * 17 + q_own];
                vv[i] = (kk < limit) ? vx : -3.0e38f;
            }
            float mx = fmaxf(fmaxf(fmaxf(vv[0], vv[1]), fmaxf(vv[2], vv[3])),
                             fmaxf(fmaxf(vv[4], vv[5]), fmaxf(vv[6], vv[7])));
            if (mx > thr) {
                int kb = p * 64 + kq * 16 + bb * 8;
#pragma unroll
                for (int i = 0; i < 8; i++)
                    if (vv[i] > thr) { ins16(vv[i], kb + i, tv, tix); thr = tv[15]; }
            }
        }
    }

    __syncthreads();
    float* scv = (float*)sm;             // 128 q x 64 entries
    int*   sci = (int*)(sm + 32768);
    {
        int q = qg * 16 + q_own;
#pragma unroll
        for (int j = 0; j < 16; j++) {
            scv[q * 64 + kq * 16 + j] = tv[j];
            sci[q * 64 + kq * 16 + j] = tix[j];
        }
    }
    __syncthreads();
    if (tid < 128) {
        float fv[16]; int fi[16];
#pragma unroll
        for (int j = 0; j < 16; j++) { fv[j] = -3.0e38f; fi[j] = 0; }
        for (int e = 0; e < 64; e++) {
            float vx = scv[tid * 64 + e];
            if (vx > fv[15]) ins16(vx, sci[tid * 64 + e], fv, fi);
        }
        int ob = (blockIdx.x * 128 + tid) * 16;
#pragma unroll
        for (int j = 0; j < 16; j++) { cval[ob + j] = fv[j]; cidx[ob + j] = fi[j]; }
    }
}

// ---------------- merge candidates, softmax, gather memory_values, fuse
__global__ __launch_bounds__(256) void k_merge(
    const float* __restrict__ cval, const int* __restrict__ cidx,
    const float* __restrict__ base, const float* __restrict__ mvals,
    const float* __restrict__ fw, float* __restrict__ out)
{
    __shared__ float sv[NCAND];
    __shared__ int   si[NCAND];
    __shared__ float wv[4]; __shared__ int wi[4];
    __shared__ float tvs[16]; __shared__ int tis[16];
    const int q = blockIdx.x, tid = threadIdx.x;
    for (int i = tid; i < NCAND; i += 256) {
        sv[i] = cval[(i >> 4) * 2048 + q * 16 + (i & 15)];
        si[i] = cidx[(i >> 4) * 2048 + q * 16 + (i & 15)];
    }
    __syncthreads();
    for (int r = 0; r < 16; r++) {
        float bv = -3.0e38f; int bp = -1;
        for (int i = tid; i < NCAND; i += 256) {
            float v = sv[i];
            if (v > bv) { bv = v; bp = i; }
        }
#pragma unroll
        for (int o = 32; o; o >>= 1) {
            float ov = __shfl_down(bv, o); int op = __shfl_down(bp, o);
            if (ov > bv) { bv = ov; bp = op; }
        }
        if ((tid & 63) == 0) { wv[tid >> 6] = bv; wi[tid >> 6] = bp; }
        __syncthreads();
        if (tid == 0) {
            float b2 = wv[0]; int p2 = wi[0];
            for (int ww = 1; ww < 4; ww++) if (wv[ww] > b2) { b2 = wv[ww]; p2 = wi[ww]; }
            tvs[r] = b2; tis[r] = si[p2]; sv[p2] = -3.0e38f;
        }
        __syncthreads();
    }
    float alpha = 1.f / (1.f + __expf(-fw[0]));
    if (tid < PDIM) {
        float m = tvs[0];
#pragma unroll
        for (int r = 1; r < 16; r++) m = fmaxf(m, tvs[r]);
        float wgt[16]; float s = 0.f;
#pragma unroll
        for (int r = 0; r < 16; r++) { wgt[r] = __expf(tvs[r] - m); s += wgt[r]; }
        float inv = 1.f / s;
        float ret = 0.f;
#pragma unroll
        for (int r = 0; r < 16; r++) ret += wgt[r] * inv * mvals[(long)tis[r] * PDIM + tid];
        out[q * PDIM + tid] = alpha * base[q * PDIM + tid] + (1.f - alpha) * ret;
    }
}

// ---------------- launch
extern "C" void kernel_launch(void* const* d_in, const int* in_sizes, int n_in,
                              void* d_out, int out_size, void* d_ws, size_t ws_size,
                              hipStream_t stream)
{
    const float* x      = (const float*)d_in[0];
    const float* keys   = (const float*)d_in[1];
    const float* mvals  = (const float*)d_in[2];
    const float* wpe    = (const float*)d_in[3];
    const float* w_in   = (const float*)d_in[4];
    const float* b_in   = (const float*)d_in[5];
    const float* ln1_g  = (const float*)d_in[6];
    const float* ln1_b  = (const float*)d_in[7];
    const float* attn_w = (const float*)d_in[8];
    const float* attn_b = (const float*)d_in[9];
    const float* attn_pw= (const float*)d_in[10];
    const float* attn_pb= (const float*)d_in[11];
    const float* ln2_g  = (const float*)d_in[12];
    const float* ln2_b  = (const float*)d_in[13];
    const float* fc_w   = (const float*)d_in[14];
    const float* fc_b   = (const float*)d_in[15];
    const float* mlp_pw = (const float*)d_in[16];
    const float* mlp_pb = (const float*)d_in[17];
    const float* lnf_g  = (const float*)d_in[18];
    const float* lnf_b  = (const float*)d_in[19];
    const float* w_out  = (const float*)d_in[20];
    const float* b_out  = (const float*)d_in[21];
    const float* ret_w1 = (const float*)d_in[22];
    const float* ret_b1 = (const float*)d_in[23];
    const float* ret_w2 = (const float*)d_in[24];
    const float* ret_b2 = (const float*)d_in[25];
    const float* fw     = (const float*)d_in[26];
    float* out = (float*)d_out;

    float* ws   = (float*)d_ws;
    float* h    = ws + 0;            // 1048576
    float* bufA = ws + 1048576;      // 1048576 (attn out / lnf out)
    float* bufB = ws + 2097152;      // 4194304 (qkv / fc act)
    float* bufO = ws + 6291456;      // 1048576 (retrieval embed)
    float* part = ws + 7340032;      // 2359296
    float* base = ws + 9699328;      // 18432
    float* qe   = ws + 9717760;      // 16384
    float* ssq  = ws + 9734144;      // 128
    short* qfh  = (short*)(ws + 9734272);   // 16384 shorts
    short* qfl  = (short*)(ws + 9742464);   // 16384 shorts
    float* cval = bufB;                     // alias: bufB dead after backbone
    int*   cidx = (int*)part;               // alias: part dead after redheads

    k_embed2<<<8192, 256, 0, stream>>>(x, w_in, b_in, wpe, h, ret_w1, ret_b1, bufO);
    for (int l = 0; l < 3; l++) {
        k_gemmln<0><<<dim3(128, 6), 256, 0, stream>>>(h, ln1_g + l * 128,
            ln1_b + l * 128, attn_w + l * 49152, attn_b + l * 384, bufB, 384);
        k_attn<<<512, 256, 0, stream>>>(bufB, bufA);
        k_gemm<128><<<dim3(128, 2), 256, 0, stream>>>(bufA, attn_pw + l * 16384,
            attn_pb + l * 128, h, h, 128);
        k_gemmln<1><<<dim3(128, 8), 256, 0, stream>>>(h, ln2_g + l * 128,
            ln2_b + l * 128, fc_w + l * 65536, fc_b + l * 512, bufB, 512);
        k_gemm<512><<<dim3(128, 2), 256, 0, stream>>>(bufB, mlp_pw + l * 65536,
            mlp_pb + l * 128, h, h, 128);
    }
    k_ln<<<2048, 256, 0, stream>>>(h, lnf_g, lnf_b, bufA);
    k_head<144><<<KSPLIT, 256, 0, stream>>>(bufA, w_out, part);
    k_redhead<<<72, 256, 0, stream>>>(part, b_out, base, 128 * 144, 144);

    k_head<128><<<KSPLIT, 256, 0, stream>>>(bufO, ret_w2, part);
    k_redhead_qe<<<64, 256, 0, stream>>>(part, ret_b2, qe, ssq);
    k_qprep<<<64, 256, 0, stream>>>(qe, ssq, qfh, qfl);

    k_sim3<<<SB, 512, 0, stream>>>(keys, qfh, qfl, cval, cidx);
    k_merge<<<128, 256, 0, stream>>>(cval, cidx, base, mvals, fw, out);
}